// Round 5
// baseline (76.737 us; speedup 1.0000x reference)
//
#include <hip/hip_runtime.h>
#include <math.h>

#define DIM 4096
#define NQ 12
#define NLAYERS 5
#define TPB 64
#define NGATES 72   // 6 layers x 12 qubits

typedef float v2f __attribute__((ext_vector_type(2)));
typedef float v4f __attribute__((ext_vector_type(4)));

// ---- scalar complex helpers (setup only) ----
__device__ __forceinline__ float2 cmul(float2 a, float2 b) {
    return make_float2(a.x * b.x - a.y * b.y, a.x * b.y + a.y * b.x);
}
__device__ __forceinline__ float2 cadd(float2 a, float2 b) {
    return make_float2(a.x + b.x, a.y + b.y);
}
__device__ __forceinline__ void mat2mul(const float2 A[4], const float2 B[4], float2 C[4]) {
    C[0] = cadd(cmul(A[0], B[0]), cmul(A[1], B[2]));
    C[1] = cadd(cmul(A[0], B[1]), cmul(A[1], B[3]));
    C[2] = cadd(cmul(A[2], B[0]), cmul(A[3], B[2]));
    C[3] = cadd(cmul(A[2], B[1]), cmul(A[3], B[3]));
}

// ---- packed complex butterfly: (a0,a1) <- U * (a0,a1) ----
// A = (u00.re,u00.im,u01.re,u01.im), B = (u10.re,u10.im,u11.re,u11.im)
__device__ __forceinline__ void bfly(v2f& a0, v2f& a1, v4f A, v4f B) {
    const v2f t0 = {-a0.y, a0.x};
    const v2f t1 = {-a1.y, a1.x};
    v2f n0 = A.x * a0;
    n0 += A.y * t0;
    n0 += A.z * a1;
    n0 += A.w * t1;
    v2f n1 = B.x * a0;
    n1 += B.y * t0;
    n1 += B.z * a1;
    n1 += B.w * t1;
    a0 = n0; a1 = n1;
}

// Gate on register-local bit LB of the 64 register-resident amplitudes.
template<int LB>
__device__ __forceinline__ void gate_on_bit(v2f (&r)[64], const v2f* __restrict__ g) {
    const v4f A = *reinterpret_cast<const v4f*>(g);
    const v4f B = *reinterpret_cast<const v4f*>(g + 2);
    constexpr int m = 1 << LB;
    #pragma unroll
    for (int j = 0; j < 64; ++j) {
        if (!(j & m)) bfly(r[j], r[j + m], A, B);
    }
}

// Layouts (state index i, 12 bits, bit0 = LSB; qubit q <-> bit 11-q):
//   H layout: thread t, reg j  <->  i = (j<<6) | t   (bits 6-11 local)
//   L layout: thread t, reg j  <->  i = (t<<6) | j   (bits 0-5  local)
// LDS storage is always thread-major with XOR swizzle sig(t)=2*(t&7):
//   thread tw writes reg jw at slot (tw<<6) | (jw ^ sig(tw))
// Ring-of-CNOT perm (verified R1-R4): new[i] = old[y], y = i^(i>>1)^((i&1)*0xC00)

__global__ __launch_bounds__(TPB, 1) void qsim_kernel(const float* __restrict__ x,
                                                      const float* __restrict__ w,
                                                      float* __restrict__ out) {
    __shared__ __align__(16) v2f st[DIM];           // 32 KB
    __shared__ __align__(16) v2f gmat[NGATES * 4];  // 2.25 KB

    const int t = threadIdx.x;
    const int b = blockIdx.x;

    // ---- build fused per-qubit gate matrices ----
    for (int gi = t; gi < NGATES; gi += TPB) {
        const int l = gi / NQ;
        const int q = gi % NQ;
        const float* pp = w + (l < NLAYERS ? l * (3 * NQ) : NLAYERS * (3 * NQ)) + q * 3;
        float s0, c0, s1, c1, s2, c2;
        sincosf(0.5f * pp[0], &s0, &c0);
        sincosf(0.5f * pp[1], &s1, &c1);
        sincosf(0.5f * pp[2], &s2, &c2);
        float2 U[4], M[4];
        if (l < NLAYERS) {
            // U = Rz(p2) * Ry(p1) * Rx(p0)
            float2 RX[4] = { {c0, 0.f}, {0.f, -s0}, {0.f, -s0}, {c0, 0.f} };
            float2 RY[4] = { {c1, 0.f}, {-s1, 0.f}, {s1, 0.f}, {c1, 0.f} };
            float2 RZ[4] = { {c2, -s2}, {0.f, 0.f}, {0.f, 0.f}, {c2, s2} };
            mat2mul(RY, RX, M);
            mat2mul(RZ, M, U);
        } else {
            // U = Ry(p2) * Rz(p1) * Ry(p0)
            float2 RY0[4] = { {c0, 0.f}, {-s0, 0.f}, {s0, 0.f}, {c0, 0.f} };
            float2 RZ1[4] = { {c1, -s1}, {0.f, 0.f}, {0.f, 0.f}, {c1, s1} };
            float2 RY2[4] = { {c2, 0.f}, {-s2, 0.f}, {s2, 0.f}, {c2, 0.f} };
            mat2mul(RZ1, RY0, M);
            mat2mul(RY2, M, U);
        }
        gmat[gi * 4 + 0] = (v2f){U[0].x, U[0].y};
        gmat[gi * 4 + 1] = (v2f){U[1].x, U[1].y};
        gmat[gi * 4 + 2] = (v2f){U[2].x, U[2].y};
        gmat[gi * 4 + 3] = (v2f){U[3].x, U[3].y};
    }

    // ---- load x in H layout (coalesced), compute sum of squares ----
    const float* xb = x + (size_t)b * DIM;
    v2f r[64];
    float ss = 0.f;
    #pragma unroll
    for (int j = 0; j < 64; ++j) {
        const float v = xb[(j << 6) + t];
        r[j] = (v2f){v, 0.f};
        ss += v * v;
    }
    #pragma unroll
    for (int o = 1; o < 64; o <<= 1) ss += __shfl_xor(ss, o, 64);
    const float inv = 1.0f / sqrtf(sqrtf(ss) + 1e-12f);
    #pragma unroll
    for (int j = 0; j < 64; ++j) r[j].x *= inv;

    // ---- precomputed address bases (element indices into st) ----
    const int sig = 2 * (t & 7);
    int wbase[8];   // write: slot = wbase[(j>>1)&7] + (j & 0x30), j even (b128 pair)
    int rbase[8];   // cross read: slot = rbase[j&7] + (j<<6)
    #pragma unroll
    for (int m = 0; m < 8; ++m) {
        wbase[m] = (t << 6) | ((2 * m) ^ sig);
        rbase[m] = t ^ (2 * m);
    }
    const int eterm = (t & 1) * 0xC00;   // perm high-bit term
    const int hh = t ^ (t >> 1);         // perm low Gray term

    __syncthreads();   // gmat visible

    // ---- circuit: 12 phases (6 layers x {H: qubits 5..0, L: qubits 11..6}) ----
    #pragma unroll 1
    for (int s = 0; s < 12; ++s) {
        const int layer = s >> 1;
        const v2f* gp = gmat + 4 * (12 * layer + ((s & 1) ? 11 : 5));
        // state bit (base+k) <-> qubit (11-base-k); gate k at gp - 4k
        gate_on_bit<0>(r, gp);
        gate_on_bit<1>(r, gp - 4);
        gate_on_bit<2>(r, gp - 8);
        gate_on_bit<3>(r, gp - 12);
        gate_on_bit<4>(r, gp - 16);
        gate_on_bit<5>(r, gp - 20);

        // write thread-major (b128 pairs, swizzled, conflict-free)
        #pragma unroll
        for (int j = 0; j < 64; j += 2) {
            const int idx = wbase[(j >> 1) & 7] + (j & 0x30);
            *reinterpret_cast<v4f*>(&st[idx]) =
                (v4f){r[j].x, r[j].y, r[j + 1].x, r[j + 1].y};
        }
        __syncthreads();

        if ((s & 1) && s < 11) {
            // after L phase (layers 0-4): fused CNOT-ring perm, read into H layout
            // want amp y = perm((j<<6)|t) from L-thread-major storage:
            //   yH = g(j) ^ (t&1)*0x30, yL = hh ^ ((j&1)<<5)
            //   slot = (yH<<6) + (yL ^ 2*(yH&7))
            #pragma unroll
            for (int j = 0; j < 64; ++j) {
                const int gj = j ^ (j >> 1);
                const int K = ((j & 1) << 5) ^ (2 * (gj & 7));
                r[j] = st[(eterm ^ (gj << 6)) + (hh ^ K)];
            }
        } else {
            // cross transpose (H<->L swap; also final output read): conflict-free
            #pragma unroll
            for (int j = 0; j < 64; ++j) {
                r[j] = st[rbase[j & 7] + (j << 6)];
            }
        }
        __syncthreads();
    }

    // ---- after s=11 cross-read: H layout -> coalesced store of real parts ----
    float* ob = out + (size_t)b * DIM;
    #pragma unroll
    for (int j = 0; j < 64; ++j) {
        ob[(j << 6) + t] = r[j].x;
    }
}

extern "C" void kernel_launch(void* const* d_in, const int* in_sizes, int n_in,
                              void* d_out, int out_size, void* d_ws, size_t ws_size,
                              hipStream_t stream) {
    const float* x = (const float*)d_in[0];      // [1024, 4096] f32
    const float* w = (const float*)d_in[1];      // [216] f32
    float* out = (float*)d_out;                  // [1024, 4096] f32
    qsim_kernel<<<dim3(1024), dim3(TPB), 0, stream>>>(x, w, out);
}

// Round 6
// 69.932 us; speedup vs baseline: 1.0973x; 1.0973x over previous
//
#include <hip/hip_runtime.h>
#include <math.h>

#define DIM 4096
#define NQ 12
#define NLAYERS 5
#define TPB 256
#define NGATES 72   // 6 layers x 12 qubits

typedef float v2f __attribute__((ext_vector_type(2)));
typedef float v4f __attribute__((ext_vector_type(4)));

// ---- scalar complex helpers (setup only) ----
__device__ __forceinline__ float2 cmul(float2 a, float2 b) {
    return make_float2(a.x * b.x - a.y * b.y, a.x * b.y + a.y * b.x);
}
__device__ __forceinline__ float2 cadd(float2 a, float2 b) {
    return make_float2(a.x + b.x, a.y + b.y);
}
__device__ __forceinline__ void mat2mul(const float2 A[4], const float2 B[4], float2 C[4]) {
    C[0] = cadd(cmul(A[0], B[0]), cmul(A[1], B[2]));
    C[1] = cadd(cmul(A[0], B[1]), cmul(A[1], B[3]));
    C[2] = cadd(cmul(A[2], B[0]), cmul(A[3], B[2]));
    C[3] = cadd(cmul(A[2], B[1]), cmul(A[3], B[3]));
}

// Compiler-level fence: forbids reordering LDS ops across this point.
// Correctness relies on per-wave in-order LDS execution (same-wave RAW/WAR on
// LDS is safe without s_barrier); this only pins the compiler's program order.
#define LDS_FENCE() asm volatile("" ::: "memory")

// ---- packed complex butterfly: (a0,a1) <- U * (a0,a1) ----
// A = (u00.re,u00.im,u01.re,u01.im), B = (u10.re,u10.im,u11.re,u11.im)
__device__ __forceinline__ void bfly(v2f& a0, v2f& a1, v4f A, v4f B) {
    const v2f t0 = {-a0.y, a0.x};
    const v2f t1 = {-a1.y, a1.x};
    v2f n0 = A.x * a0;
    n0 += A.y * t0;
    n0 += A.z * a1;
    n0 += A.w * t1;
    v2f n1 = B.x * a0;
    n1 += B.y * t0;
    n1 += B.z * a1;
    n1 += B.w * t1;
    a0 = n0; a1 = n1;
}

// Gate on register-local bit LB (global bit LB, qubit 11-LB).
template<int LB>
__device__ __forceinline__ void gate_on_bit(v2f (&r)[16], const v2f* __restrict__ g) {
    const v4f A = *reinterpret_cast<const v4f*>(g);
    const v4f B = *reinterpret_cast<const v4f*>(g + 2);
    constexpr int m = 1 << LB;
    #pragma unroll
    for (int j = 0; j < 16; ++j) {
        if (!(j & m)) bfly(r[j], r[j + m], A, B);
    }
}

template<int BETA>
__device__ __forceinline__ void apply_phase(v2f (&r)[16], const v2f* __restrict__ gm, int goff) {
    gate_on_bit<0>(r, gm + 4 * (goff + 11 - BETA - 0));
    gate_on_bit<1>(r, gm + 4 * (goff + 11 - BETA - 1));
    gate_on_bit<2>(r, gm + 4 * (goff + 11 - BETA - 2));
    gate_on_bit<3>(r, gm + 4 * (goff + 11 - BETA - 3));
}

__global__ __launch_bounds__(TPB) void qsim_kernel(const float* __restrict__ x,
                                                   const float* __restrict__ w,
                                                   float* __restrict__ out) {
    // XOR bank-swizzled state buffer: amplitude i lives at slot S(i) = i ^ ((i>>3)&14)
    __shared__ __align__(16) v2f st[DIM];           // 32 KB
    __shared__ __align__(16) v2f gmat[NGATES * 4];  // 2.25 KB
    __shared__ float red[4];

    const int tid = threadIdx.x;
    const int b = blockIdx.x;

    // ---- build fused per-qubit gate matrices (threads 0..71) ----
    if (tid < NGATES) {
        const int l = tid / NQ;
        const int q = tid % NQ;
        const float* pp = w + (l < NLAYERS ? l * (3 * NQ) : NLAYERS * (3 * NQ)) + q * 3;
        float s0, c0, s1, c1, s2, c2;
        sincosf(0.5f * pp[0], &s0, &c0);
        sincosf(0.5f * pp[1], &s1, &c1);
        sincosf(0.5f * pp[2], &s2, &c2);
        float2 U[4], M[4];
        if (l < NLAYERS) {
            // U = Rz(p2) * Ry(p1) * Rx(p0)
            float2 RX[4] = { {c0, 0.f}, {0.f, -s0}, {0.f, -s0}, {c0, 0.f} };
            float2 RY[4] = { {c1, 0.f}, {-s1, 0.f}, {s1, 0.f}, {c1, 0.f} };
            float2 RZ[4] = { {c2, -s2}, {0.f, 0.f}, {0.f, 0.f}, {c2, s2} };
            mat2mul(RY, RX, M);
            mat2mul(RZ, M, U);
        } else {
            // U = Ry(p2) * Rz(p1) * Ry(p0)
            float2 RY0[4] = { {c0, 0.f}, {-s0, 0.f}, {s0, 0.f}, {c0, 0.f} };
            float2 RZ1[4] = { {c1, -s1}, {0.f, 0.f}, {0.f, 0.f}, {c1, s1} };
            float2 RY2[4] = { {c2, 0.f}, {-s2, 0.f}, {s2, 0.f}, {c2, 0.f} };
            mat2mul(RZ1, RY0, M);
            mat2mul(RY2, M, U);
        }
        gmat[tid * 4 + 0] = (v2f){U[0].x, U[0].y};
        gmat[tid * 4 + 1] = (v2f){U[1].x, U[1].y};
        gmat[tid * 4 + 2] = (v2f){U[2].x, U[2].y};
        gmat[tid * 4 + 3] = (v2f){U[3].x, U[3].y};
    }

    // ---- load x in C layout (i = 16*tid + j), compute sum of squares ----
    const float* xb = x + (size_t)b * DIM;
    v2f r[16];
    float ss = 0.f;
    {
        const float4* xv = reinterpret_cast<const float4*>(xb + 16 * tid);
        #pragma unroll
        for (int k = 0; k < 4; ++k) {
            float4 v = xv[k];
            r[k * 4 + 0] = (v2f){v.x, 0.f};
            r[k * 4 + 1] = (v2f){v.y, 0.f};
            r[k * 4 + 2] = (v2f){v.z, 0.f};
            r[k * 4 + 3] = (v2f){v.w, 0.f};
            ss += v.x * v.x + v.y * v.y + v.z * v.z + v.w * v.w;
        }
    }
    #pragma unroll
    for (int off = 32; off > 0; off >>= 1) ss += __shfl_down(ss, off, 64);
    if ((tid & 63) == 0) red[tid >> 6] = ss;
    __syncthreads();   // covers gmat + red (cross-wave: REQUIRED)

    const float total = red[0] + red[1] + red[2] + red[3];
    const float inv = 1.0f / sqrtf(sqrtf(total) + 1e-12f);
    #pragma unroll
    for (int j = 0; j < 16; ++j) { r[j].x *= inv; }

    // per-thread layout constants
    const int cxor = (tid & 7) << 1;                     // C-layout slot xor
    const int bbase = (tid >> 4) << 8;                   // B-layout base
    const int tl = tid & 15;                             // B-layout low bits
    const int tA = tid ^ (((tid >> 4) & 7) << 1);        // A-layout slot low byte

    // Barrier audit (i[11:10] == tid[7:6] in both C and B layouts):
    //  - C-write slots [16 tid, 16 tid+16) and B-read slots bbase|(j<<4)|...
    //    both lie in the wave's private quarter [1024 w, 1024 w+1024):
    //    same-wave in-order LDS => NO barrier around C->B.
    //  - B-write set == B-read set per thread => no barrier before B-write.
    //  - A-read set {(j<<8)|tA} == perm-write set per thread, tA bijective
    //    => cross-thread disjoint => NO barrier between them.
    //  - Kept: after B-write (A-read is cross-wave), after perm-write
    //    (perm-read is cross-wave), after perm-read (next C-write reuses st).

    // ---- circuit ----
    for (int l = 0; l < NLAYERS + 1; ++l) {
        const int goff = 12 * l;

        // phase C: bits 0-3 (qubits 11..8)
        apply_phase<0>(r, gmat, goff);

        // transpose C -> B (wave-private: no barrier, program order suffices)
        #pragma unroll
        for (int j = 0; j < 16; j += 2) {
            *reinterpret_cast<v4f*>(&st[16 * tid + (j ^ cxor)]) =
                (v4f){r[j].x, r[j].y, r[j + 1].x, r[j + 1].y};
        }
        LDS_FENCE();
        #pragma unroll
        for (int j = 0; j < 16; ++j) {
            r[j] = st[bbase | (j << 4) | (tl ^ ((j & 7) << 1))];
        }
        LDS_FENCE();

        // phase B: bits 4-7 (qubits 7..4)
        apply_phase<4>(r, gmat, goff);

        // transpose B -> A (write set == read set per thread: no pre-barrier;
        // A-read is cross-wave: barrier after the write)
        #pragma unroll
        for (int j = 0; j < 16; ++j) {
            st[bbase | (j << 4) | (tl ^ ((j & 7) << 1))] = r[j];
        }
        __syncthreads();
        #pragma unroll
        for (int j = 0; j < 16; ++j) {
            r[j] = st[(j << 8) | tA];
        }
        LDS_FENCE();

        // phase A: bits 8-11 (qubits 3..0)
        apply_phase<8>(r, gmat, goff);

        if (l == NLAYERS) break;   // final layer: no ring of CNOTs

        // ring-of-CNOT permutation fused into transpose A -> C:
        // new[i] = old[y(i)], y = i ^ (i>>1) ^ ((i&1)*0xC00)
        // perm-write set == this thread's A-read set: no pre-barrier needed.
        #pragma unroll
        for (int j = 0; j < 16; ++j) {
            st[(j << 8) | tA] = r[j];
        }
        __syncthreads();
        #pragma unroll
        for (int j = 0; j < 16; ++j) {
            const int i = 16 * tid + j;
            int y = i ^ (i >> 1);
            y ^= (i & 1) * 0xC00;
            r[j] = st[y ^ ((y >> 3) & 14)];
        }
        __syncthreads();   // next layer's C-write reuses st: REQUIRED
    }

    // ---- store real part from A layout: i = (j<<8) | tid -> coalesced ----
    float* ob = out + (size_t)b * DIM;
    #pragma unroll
    for (int j = 0; j < 16; ++j) {
        ob[(j << 8) | tid] = r[j].x;
    }
}

extern "C" void kernel_launch(void* const* d_in, const int* in_sizes, int n_in,
                              void* d_out, int out_size, void* d_ws, size_t ws_size,
                              hipStream_t stream) {
    const float* x = (const float*)d_in[0];      // [1024, 4096] f32
    const float* w = (const float*)d_in[1];      // [216] f32
    float* out = (float*)d_out;                  // [1024, 4096] f32
    qsim_kernel<<<dim3(1024), dim3(TPB), 0, stream>>>(x, w, out);
}

// Round 7
// 62.695 us; speedup vs baseline: 1.2240x; 1.1154x over previous
//
#include <hip/hip_runtime.h>
#include <math.h>

#define DIM 4096
#define NQ 12
#define NLAYERS 5
#define TPB 256
#define NGATES 72   // 6 layers x 12 qubits

typedef float v2f __attribute__((ext_vector_type(2)));
typedef float v4f __attribute__((ext_vector_type(4)));

// ---- scalar complex helpers (setup only) ----
__device__ __forceinline__ float2 cmul(float2 a, float2 b) {
    return make_float2(a.x * b.x - a.y * b.y, a.x * b.y + a.y * b.x);
}
__device__ __forceinline__ float2 cadd(float2 a, float2 b) {
    return make_float2(a.x + b.x, a.y + b.y);
}
__device__ __forceinline__ void mat2mul(const float2 A[4], const float2 B[4], float2 C[4]) {
    C[0] = cadd(cmul(A[0], B[0]), cmul(A[1], B[2]));
    C[1] = cadd(cmul(A[0], B[1]), cmul(A[1], B[3]));
    C[2] = cadd(cmul(A[2], B[0]), cmul(A[3], B[2]));
    C[3] = cadd(cmul(A[2], B[1]), cmul(A[3], B[3]));
}

#define LDS_FENCE() asm volatile("" ::: "memory")

// ---- forced VOP3P packed-f32 complex math ----
// d = {c.lo*s.lo, c.lo*s.hi}            (broadcast src0.lo)
__device__ __forceinline__ v2f pk_mul_bc(v2f c, v2f s) {
    v2f d;
    asm("v_pk_mul_f32 %0, %1, %2 op_sel:[0,0] op_sel_hi:[0,1]"
        : "=v"(d) : "v"(c), "v"(s));
    return d;
}
// d = {c.lo*s.lo + a.lo, c.lo*s.hi + a.hi}
__device__ __forceinline__ v2f pk_fma_bc(v2f c, v2f s, v2f a) {
    v2f d;
    asm("v_pk_fma_f32 %0, %1, %2, %3 op_sel:[0,0,0] op_sel_hi:[0,1,1]"
        : "=v"(d) : "v"(c), "v"(s), "v"(a));
    return d;
}
// d = {c.lo*s.hi + a.lo, c.hi*s.lo + a.hi}   (src1 halves crossed)
__device__ __forceinline__ v2f pk_fma_swap(v2f c, v2f s, v2f a) {
    v2f d;
    asm("v_pk_fma_f32 %0, %1, %2, %3 op_sel:[0,1,0] op_sel_hi:[1,0,1]"
        : "=v"(d) : "v"(c), "v"(s), "v"(a));
    return d;
}

// complex butterfly: (a0,a1) <- U*(a0,a1), u*n = {-u*.im, +u*.im}
// n0 = u00.re*a0 + {-u00.im,+u00.im}*swap(a0) + u01.re*a1 + {-u01.im,+u01.im}*swap(a1)
__device__ __forceinline__ void bfly(v2f& a0, v2f& a1,
                                     v2f u00, v2f u00n, v2f u01, v2f u01n,
                                     v2f u10, v2f u10n, v2f u11, v2f u11n) {
    v2f n0 = pk_mul_bc(u00, a0);
    n0 = pk_fma_swap(u00n, a0, n0);
    n0 = pk_fma_bc(u01, a1, n0);
    n0 = pk_fma_swap(u01n, a1, n0);
    v2f n1 = pk_mul_bc(u10, a0);
    n1 = pk_fma_swap(u10n, a0, n1);
    n1 = pk_fma_bc(u11, a1, n1);
    n1 = pk_fma_swap(u11n, a1, n1);
    a0 = n0; a1 = n1;
}

// Gate on register-local bit LB (global bit LB, qubit 11-LB).
template<int LB>
__device__ __forceinline__ void gate_on_bit(v2f (&r)[16], const v2f* __restrict__ g) {
    const v4f AB0 = *reinterpret_cast<const v4f*>(g);       // u00, u01
    const v4f AB1 = *reinterpret_cast<const v4f*>(g + 2);   // u10, u11
    const v2f u00 = {AB0.x, AB0.y}, u01 = {AB0.z, AB0.w};
    const v2f u10 = {AB1.x, AB1.y}, u11 = {AB1.z, AB1.w};
    const v2f u00n = {-AB0.y, AB0.y}, u01n = {-AB0.w, AB0.w};
    const v2f u10n = {-AB1.y, AB1.y}, u11n = {-AB1.w, AB1.w};
    constexpr int m = 1 << LB;
    #pragma unroll
    for (int j = 0; j < 16; ++j) {
        if (!(j & m)) bfly(r[j], r[j + m], u00, u00n, u01, u01n, u10, u10n, u11, u11n);
    }
}

template<int BETA>
__device__ __forceinline__ void apply_phase(v2f (&r)[16], const v2f* __restrict__ gm, int goff) {
    gate_on_bit<0>(r, gm + 4 * (goff + 11 - BETA - 0));
    gate_on_bit<1>(r, gm + 4 * (goff + 11 - BETA - 1));
    gate_on_bit<2>(r, gm + 4 * (goff + 11 - BETA - 2));
    gate_on_bit<3>(r, gm + 4 * (goff + 11 - BETA - 3));
}

__global__ __launch_bounds__(TPB) void qsim_kernel(const float* __restrict__ x,
                                                   const float* __restrict__ w,
                                                   float* __restrict__ out) {
    // XOR bank-swizzled state buffer: amplitude i lives at slot S(i) = i ^ ((i>>3)&14)
    __shared__ __align__(16) v2f st[DIM];           // 32 KB
    __shared__ __align__(16) v2f gmat[NGATES * 4];  // 2.25 KB
    __shared__ float red[4];

    const int tid = threadIdx.x;
    const int b = blockIdx.x;

    // ---- build fused per-qubit gate matrices (threads 0..71) ----
    if (tid < NGATES) {
        const int l = tid / NQ;
        const int q = tid % NQ;
        const float* pp = w + (l < NLAYERS ? l * (3 * NQ) : NLAYERS * (3 * NQ)) + q * 3;
        float s0, c0, s1, c1, s2, c2;
        sincosf(0.5f * pp[0], &s0, &c0);
        sincosf(0.5f * pp[1], &s1, &c1);
        sincosf(0.5f * pp[2], &s2, &c2);
        float2 U[4], M[4];
        if (l < NLAYERS) {
            // U = Rz(p2) * Ry(p1) * Rx(p0)
            float2 RX[4] = { {c0, 0.f}, {0.f, -s0}, {0.f, -s0}, {c0, 0.f} };
            float2 RY[4] = { {c1, 0.f}, {-s1, 0.f}, {s1, 0.f}, {c1, 0.f} };
            float2 RZ[4] = { {c2, -s2}, {0.f, 0.f}, {0.f, 0.f}, {c2, s2} };
            mat2mul(RY, RX, M);
            mat2mul(RZ, M, U);
        } else {
            // U = Ry(p2) * Rz(p1) * Ry(p0)
            float2 RY0[4] = { {c0, 0.f}, {-s0, 0.f}, {s0, 0.f}, {c0, 0.f} };
            float2 RZ1[4] = { {c1, -s1}, {0.f, 0.f}, {0.f, 0.f}, {c1, s1} };
            float2 RY2[4] = { {c2, 0.f}, {-s2, 0.f}, {s2, 0.f}, {c2, 0.f} };
            mat2mul(RZ1, RY0, M);
            mat2mul(RY2, M, U);
        }
        gmat[tid * 4 + 0] = (v2f){U[0].x, U[0].y};
        gmat[tid * 4 + 1] = (v2f){U[1].x, U[1].y};
        gmat[tid * 4 + 2] = (v2f){U[2].x, U[2].y};
        gmat[tid * 4 + 3] = (v2f){U[3].x, U[3].y};
    }

    // ---- load x in C layout (i = 16*tid + j), compute sum of squares ----
    const float* xb = x + (size_t)b * DIM;
    v2f r[16];
    float ss = 0.f;
    {
        const float4* xv = reinterpret_cast<const float4*>(xb + 16 * tid);
        #pragma unroll
        for (int k = 0; k < 4; ++k) {
            float4 v = xv[k];
            r[k * 4 + 0] = (v2f){v.x, 0.f};
            r[k * 4 + 1] = (v2f){v.y, 0.f};
            r[k * 4 + 2] = (v2f){v.z, 0.f};
            r[k * 4 + 3] = (v2f){v.w, 0.f};
            ss += v.x * v.x + v.y * v.y + v.z * v.z + v.w * v.w;
        }
    }
    #pragma unroll
    for (int off = 32; off > 0; off >>= 1) ss += __shfl_down(ss, off, 64);
    if ((tid & 63) == 0) red[tid >> 6] = ss;
    __syncthreads();   // covers gmat + red (cross-wave: REQUIRED)

    const float total = red[0] + red[1] + red[2] + red[3];
    const float inv = 1.0f / sqrtf(sqrtf(total) + 1e-12f);
    #pragma unroll
    for (int j = 0; j < 16; ++j) { r[j].x *= inv; }

    // per-thread layout constants
    const int cxor = (tid & 7) << 1;                     // C-layout slot xor
    const int bbase = (tid >> 4) << 8;                   // B-layout base
    const int tl = tid & 15;                             // B-layout low bits
    const int tA = tid ^ (((tid >> 4) & 7) << 1);        // A-layout slot low byte

    // Barrier audit: see R6 — C->B is wave-private (in-order LDS per wave),
    // B-write==B-read set, A-read==perm-write set; 3 barriers/layer kept.

    // ---- circuit ----
    for (int l = 0; l < NLAYERS + 1; ++l) {
        const int goff = 12 * l;

        // phase C: bits 0-3 (qubits 11..8)
        apply_phase<0>(r, gmat, goff);

        // transpose C -> B (wave-private: no barrier)
        #pragma unroll
        for (int j = 0; j < 16; j += 2) {
            *reinterpret_cast<v4f*>(&st[16 * tid + (j ^ cxor)]) =
                (v4f){r[j].x, r[j].y, r[j + 1].x, r[j + 1].y};
        }
        LDS_FENCE();
        #pragma unroll
        for (int j = 0; j < 16; ++j) {
            r[j] = st[bbase | (j << 4) | (tl ^ ((j & 7) << 1))];
        }
        LDS_FENCE();

        // phase B: bits 4-7 (qubits 7..4)
        apply_phase<4>(r, gmat, goff);

        // transpose B -> A
        #pragma unroll
        for (int j = 0; j < 16; ++j) {
            st[bbase | (j << 4) | (tl ^ ((j & 7) << 1))] = r[j];
        }
        __syncthreads();
        #pragma unroll
        for (int j = 0; j < 16; ++j) {
            r[j] = st[(j << 8) | tA];
        }
        LDS_FENCE();

        // phase A: bits 8-11 (qubits 3..0)
        apply_phase<8>(r, gmat, goff);

        if (l == NLAYERS) break;   // final layer: no ring of CNOTs

        // ring-of-CNOT permutation fused into transpose A -> C:
        // new[i] = old[y(i)], y = i ^ (i>>1) ^ ((i&1)*0xC00)
        #pragma unroll
        for (int j = 0; j < 16; ++j) {
            st[(j << 8) | tA] = r[j];
        }
        __syncthreads();
        #pragma unroll
        for (int j = 0; j < 16; ++j) {
            const int i = 16 * tid + j;
            int y = i ^ (i >> 1);
            y ^= (i & 1) * 0xC00;
            r[j] = st[y ^ ((y >> 3) & 14)];
        }
        __syncthreads();   // next layer's C-write reuses st: REQUIRED
    }

    // ---- store real part from A layout: i = (j<<8) | tid -> coalesced ----
    float* ob = out + (size_t)b * DIM;
    #pragma unroll
    for (int j = 0; j < 16; ++j) {
        ob[(j << 8) | tid] = r[j].x;
    }
}

extern "C" void kernel_launch(void* const* d_in, const int* in_sizes, int n_in,
                              void* d_out, int out_size, void* d_ws, size_t ws_size,
                              hipStream_t stream) {
    const float* x = (const float*)d_in[0];      // [1024, 4096] f32
    const float* w = (const float*)d_in[1];      // [216] f32
    float* out = (float*)d_out;                  // [1024, 4096] f32
    qsim_kernel<<<dim3(1024), dim3(TPB), 0, stream>>>(x, w, out);
}

// Round 8
// 51.577 us; speedup vs baseline: 1.4878x; 1.2156x over previous
//
#include <hip/hip_runtime.h>
#include <math.h>

#define NQ 12
#define NLAYERS 5
#define TPB 256

typedef float v4f __attribute__((ext_vector_type(4)));
typedef short v8s __attribute__((ext_vector_type(8)));

#define MFMA(A, B, C) __builtin_amdgcn_mfma_f32_16x16x32_bf16((A), (B), (C), 0, 0, 0)

// ---- complex helpers (gate/W build) ----
__device__ __forceinline__ float2 cmulf(float2 a, float2 b) {
    return make_float2(a.x * b.x - a.y * b.y, a.x * b.y + a.y * b.x);
}
__device__ __forceinline__ float2 caddf(float2 a, float2 b) {
    return make_float2(a.x + b.x, a.y + b.y);
}
__device__ __forceinline__ void mat2mul(const float2 A[4], const float2 B[4], float2 C[4]) {
    C[0] = caddf(cmulf(A[0], B[0]), cmulf(A[1], B[2]));
    C[1] = caddf(cmulf(A[0], B[1]), cmulf(A[1], B[3]));
    C[2] = caddf(cmulf(A[2], B[0]), cmulf(A[3], B[2]));
    C[3] = caddf(cmulf(A[2], B[1]), cmulf(A[3], B[3]));
}

// ---- packing helpers ----
__device__ __forceinline__ v8s pk4(unsigned a, unsigned b, unsigned c, unsigned d) {
    union { unsigned u[4]; v8s s; } x;
    x.u[0] = a; x.u[1] = b; x.u[2] = c; x.u[3] = d;
    return x.s;
}
__device__ __forceinline__ unsigned hsw(unsigned x) {           // swap bf16 halves
    return __builtin_amdgcn_alignbit(x, x, 16);
}
__device__ __forceinline__ unsigned cvt2(float a, float b) {    // {bf16(a) lo, bf16(b) hi}
    unsigned d;
    asm("v_cvt_pk_bf16_f32 %0, %1, %2" : "=v"(d) : "v"(a), "v"(b));
    return d;
}
// f32 -> dword {hi-bf16 (trunc) in lo16, lo-bf16 in hi16}; hi+lo == fl17(f)
__device__ __forceinline__ unsigned packhl(float f) {
    unsigned h = __float_as_uint(f) & 0xFFFF0000u;
    float lo = f - __uint_as_float(h);
    return (h >> 16) | (cvt2(lo, 0.0f) << 16);
}
// state entry {H = {Crh, Cih}, L = {Crl, Cil}}
__device__ __forceinline__ uint2 packE(float cr, float ci) {
    unsigned hr = __float_as_uint(cr) & 0xFFFF0000u;
    unsigned hi2 = __float_as_uint(ci) & 0xFFFF0000u;
    float lr = cr - __uint_as_float(hr);
    float li = ci - __uint_as_float(hi2);
    uint2 e;
    e.x = (hr >> 16) | hi2;
    e.y = cvt2(lr, li);
    return e;
}

// ---- ring-of-CNOT permutation p = y^{-1}, GF(2)-linear, field-decomposed ----
// y(i) = i ^ (i>>1) ^ ((i&1)*0xC00) (verified R1-R7); p verified: y(p(o)) == o
__device__ __forceinline__ int sx4(int x) { x ^= x >> 1; x ^= x >> 2; return x & 15; }
__device__ __forceinline__ int permR(int row) {          // p(row<<8)
    int s = sx4(row), par = s & 1;
    return ((s ^ (par << 3)) << 8) | (par ? 0xFF : 0);
}
__device__ __forceinline__ int permT(int t) {            // p(t<<4)
    int s = sx4(t), par = s & 1;
    return (par << 11) | (s << 4) | (par ? 0xF : 0);
}
__device__ __forceinline__ int permL(int lo) {           // p(lo)
    int s = sx4(lo), par = s & 1;
    return s | (par << 11);
}
// slot keying with nibble swizzle folded in: slot(p) = p ^ f4(p>>4) on low nibble
__device__ __forceinline__ int Mslot(int p) {
    return p ^ ((((p >> 4) & 3) << 2) | ((p >> 6) & 3));
}

// ---- W = Kron of 4 gates for one phase; thread computes entry (r=tid>>4, c=tid&15) ----
__device__ __forceinline__ void buildW(const float2* gm, int layer, int beta, int tid,
                                       unsigned& wrd, unsigned& wid) {
    const int r = tid >> 4, c = tid & 15;
    float2 u = make_float2(1.f, 0.f);
    #pragma unroll
    for (int bb = 0; bb < 4; ++bb) {
        // group bit bb <-> state bit (beta+bb) <-> qubit 11-beta-bb
        const float2 e = gm[(layer * 12 + 11 - beta - bb) * 4 + ((r >> bb) & 1) * 2 + ((c >> bb) & 1)];
        u = cmulf(u, e);
    }
    wrd = packhl(u.x);
    wid = packhl(u.y);
}

// ---- one phase: contract a 4-bit group with 16x16 complex W via split-bf16 MFMA ----
// WMODE: 0 = write keyed for B-group, 1 = keyed for A-group, 2 = perm-fused keyed C, 3 = global store
template<int WMODE>
__device__ __forceinline__ void phase_body(
    const float2* gm, uint2* st, unsigned* wrp, unsigned* wip,
    const int* sb, int af, const int* swcb, const int* swba, int f4l,
    int lane, int w, int tid,
    int blayer, int bbeta, bool dobuild,
    float* outp)
{
    // A fragments: dword (r=lane&15, m=4*(lane>>4)+q) = {Wh, Wl} interleaved
    const uint4 Ar = *reinterpret_cast<const uint4*>(wrp + af);
    const uint4 Ai = *reinterpret_cast<const uint4*>(wip + af);

    // raw state reads: entry (v = tile*16 + (lane&15), m = 4*(lane>>4)+q)
    uint2 rb[4][4];
    #pragma unroll
    for (int ti = 0; ti < 4; ++ti) {
        #pragma unroll
        for (int q = 0; q < 4; ++q) rb[ti][q] = st[sb[q] + ti * 256];
    }

    const unsigned NX = 0x80008000u;
    const v8s a_r1 = pk4(Ar.x, Ar.y, Ar.z, Ar.w);
    const v8s a_r2 = pk4(hsw(Ar.x), hsw(Ar.y), hsw(Ar.z), hsw(Ar.w));
    const v8s a_i1 = pk4(Ai.x, Ai.y, Ai.z, Ai.w);
    const v8s a_i2 = pk4(hsw(Ai.x), hsw(Ai.y), hsw(Ai.z), hsw(Ai.w));
    const v8s a_n1 = pk4(Ai.x ^ NX, Ai.y ^ NX, Ai.z ^ NX, Ai.w ^ NX);
    const v8s a_n2 = pk4(hsw(Ai.x) ^ NX, hsw(Ai.y) ^ NX, hsw(Ai.z) ^ NX, hsw(Ai.w) ^ NX);

    v4f accr[4], acci[4];
    #pragma unroll
    for (int ti = 0; ti < 4; ++ti) {
        unsigned sr[4], si[4];
        #pragma unroll
        for (int q = 0; q < 4; ++q) {
            // H = rb.x = {Srh, Sih}; L = rb.y = {Srl, Sil}
            sr[q] = __builtin_amdgcn_perm(rb[ti][q].y, rb[ti][q].x, 0x05040100u); // {Srh, Srl}
            si[q] = __builtin_amdgcn_perm(rb[ti][q].y, rb[ti][q].x, 0x07060302u); // {Sih, Sil}
        }
        const v8s bsr = pk4(sr[0], sr[1], sr[2], sr[3]);
        const v8s bsi = pk4(si[0], si[1], si[2], si[3]);
        v4f z = {0.f, 0.f, 0.f, 0.f};
        // Cr = (Wh+Wl)(Srh+Srl) - (Wih+Wil)(Sih+Sil), exactly via self+cross pairs
        v4f cr = MFMA(a_n2, bsi, z);
        cr = MFMA(a_n1, bsi, cr);
        cr = MFMA(a_r2, bsr, cr);
        cr = MFMA(a_r1, bsr, cr);
        v4f ci = MFMA(a_i2, bsr, z);
        ci = MFMA(a_i1, bsr, ci);
        ci = MFMA(a_r2, bsi, ci);
        ci = MFMA(a_r1, bsi, ci);
        accr[ti] = cr;
        acci[ti] = ci;
    }

    // build next phase's W entry (registers only; gmat is read-only)
    unsigned wrd = 0, wid = 0;
    if (dobuild) buildW(gm, blayer, bbeta, tid, wrd, wid);

    __syncthreads();   // all reads done -> safe to overwrite state & W planes

    if (dobuild) { wrp[tid] = wrd; wip[tid] = wid; }

    const int hl = lane >> 4;
    if (WMODE == 0) {
        // D index i = t<<8 | (lane&15)<<4 | (4hl+g); key for B-group
        #pragma unroll
        for (int ti = 0; ti < 4; ++ti) {
            #pragma unroll
            for (int g = 0; g < 4; ++g)
                st[swcb[g] + ti * 256] = packE(accr[ti][g], acci[ti][g]);
        }
    } else if (WMODE == 1) {
        // D index i = t<<8 | (4hl+g)<<4 | (lane&15); key for A-group
        #pragma unroll
        for (int ti = 0; ti < 4; ++ti) {
            const int tx = (4 * w + ti) ^ f4l;
            #pragma unroll
            for (int g = 0; g < 4; ++g)
                st[swba[g] + tx] = packE(accr[ti][g], acci[ti][g]);
        }
    } else if (WMODE == 2) {
        // D index i = (4hl+g)<<8 | t<<4 | (lane&15); apply CNOT-ring perm p, key for C-group
        const int mpl = Mslot(permL(lane & 15));
        int mprl[4];
        #pragma unroll
        for (int g = 0; g < 4; ++g)
            mprl[g] = Mslot(permR(4 * hl + g)) ^ mpl;
        #pragma unroll
        for (int ti = 0; ti < 4; ++ti) {
            const int mpt = Mslot(permT(4 * w + ti));
            #pragma unroll
            for (int g = 0; g < 4; ++g)
                st[mprl[g] ^ mpt] = packE(accr[ti][g], acci[ti][g]);
        }
    } else {
        // final phase: out[i] = Re(amp), i = (4hl+g)<<8 | t<<4 | (lane&15)
        #pragma unroll
        for (int ti = 0; ti < 4; ++ti) {
            #pragma unroll
            for (int g = 0; g < 4; ++g)
                outp[((4 * hl + g) << 8) + (4 * w + ti) * 16 + (lane & 15)] = accr[ti][g];
        }
    }
    __syncthreads();
}

__global__ __launch_bounds__(TPB, 4) void qsim_kernel(const float* __restrict__ x,
                                                      const float* __restrict__ wgt,
                                                      float* __restrict__ out) {
    __shared__ __align__(16) uint2 st[4096];        // 32 KB: {H,L} per amp, swizzled slots
    __shared__ __align__(16) unsigned wrp[256];     // 1 KB: W real {hi,lo} dwords
    __shared__ __align__(16) unsigned wip[256];     // 1 KB: W imag
    __shared__ __align__(16) float2 gmat[288];      // 2.25 KB fused 2x2 gates
    __shared__ float red[4];

    const int tid = threadIdx.x;
    const int lane = tid & 63;
    const int w = tid >> 6;
    const int b = blockIdx.x;

    // ---- fused per-qubit gate matrices (threads 0..71), same as R7 ----
    if (tid < 72) {
        const int l = tid / NQ;
        const int q = tid % NQ;
        const float* pp = wgt + (l < NLAYERS ? l * (3 * NQ) : NLAYERS * (3 * NQ)) + q * 3;
        float s0, c0, s1, c1, s2, c2;
        sincosf(0.5f * pp[0], &s0, &c0);
        sincosf(0.5f * pp[1], &s1, &c1);
        sincosf(0.5f * pp[2], &s2, &c2);
        float2 U[4], M[4];
        if (l < NLAYERS) {
            float2 RX[4] = { {c0, 0.f}, {0.f, -s0}, {0.f, -s0}, {c0, 0.f} };
            float2 RY[4] = { {c1, 0.f}, {-s1, 0.f}, {s1, 0.f}, {c1, 0.f} };
            float2 RZ[4] = { {c2, -s2}, {0.f, 0.f}, {0.f, 0.f}, {c2, s2} };
            mat2mul(RY, RX, M);
            mat2mul(RZ, M, U);
        } else {
            float2 RY0[4] = { {c0, 0.f}, {-s0, 0.f}, {s0, 0.f}, {c0, 0.f} };
            float2 RZ1[4] = { {c1, -s1}, {0.f, 0.f}, {0.f, 0.f}, {c1, s1} };
            float2 RY2[4] = { {c2, 0.f}, {-s2, 0.f}, {s2, 0.f}, {c2, 0.f} };
            mat2mul(RZ1, RY0, M);
            mat2mul(RY2, M, U);
        }
        gmat[tid * 4 + 0] = U[0];
        gmat[tid * 4 + 1] = U[1];
        gmat[tid * 4 + 2] = U[2];
        gmat[tid * 4 + 3] = U[3];
    }

    // ---- load x (i = 16*tid + j), sum of squares ----
    const float* xb = x + (size_t)b * 4096;
    float vals[16];
    float ss = 0.f;
    {
        const float4* xv = reinterpret_cast<const float4*>(xb + 16 * tid);
        #pragma unroll
        for (int k = 0; k < 4; ++k) {
            float4 v = xv[k];
            vals[k * 4 + 0] = v.x; vals[k * 4 + 1] = v.y;
            vals[k * 4 + 2] = v.z; vals[k * 4 + 3] = v.w;
            ss += v.x * v.x + v.y * v.y + v.z * v.z + v.w * v.w;
        }
    }
    #pragma unroll
    for (int off = 32; off > 0; off >>= 1) ss += __shfl_down(ss, off, 64);
    if (lane == 0) red[w] = ss;
    __syncthreads();   // gmat + red visible

    const float total = red[0] + red[1] + red[2] + red[3];
    const float inv = 1.0f / sqrtf(sqrtf(total) + 1e-12f);

    // ---- initial state, keyed for C-group: v = tid, k = j ----
    const int f4t = ((tid & 3) << 2) | ((tid >> 2) & 3);
    #pragma unroll
    for (int j = 0; j < 16; ++j) {
        const float p = vals[j] * inv;
        const unsigned h = __float_as_uint(p) & 0xFFFF0000u;
        const float lo = p - __uint_as_float(h);
        uint2 e;
        e.x = h >> 16;            // {Srh, Sih=0}
        e.y = cvt2(lo, 0.0f);     // {Srl, Sil=0}
        st[tid * 16 + (j ^ f4t)] = e;
    }

    // ---- W for phase 0 (layer 0, beta 0) ----
    {
        unsigned wrd, wid;
        buildW(gmat, 0, 0, tid, wrd, wid);
        wrp[tid] = wrd; wip[tid] = wid;
    }
    __syncthreads();

    // ---- per-lane address constants ----
    const int hl = lane >> 4;
    const int f4l = ((lane & 3) << 2) | ((lane >> 2) & 3);
    int sb[4], swcb[4], swba[4];
    #pragma unroll
    for (int q = 0; q < 4; ++q)
        sb[q] = w * 1024 + (lane & 15) * 16 + (((hl ^ (lane & 3)) << 2) | (q ^ ((lane >> 2) & 3)));
    #pragma unroll
    for (int g = 0; g < 4; ++g) {
        swcb[g] = w * 1024 + (4 * hl + g) * 16 + ((lane & 15) ^ (g << 2) ^ hl);
        swba[g] = (4 * hl + g) * 256 + (lane & 15) * 16;
    }
    const int af = (lane & 15) * 16 + hl * 4;
    float* outp = out + (size_t)b * 4096;

    // ---- circuit: 6 layers x 3 phases ----
    #pragma unroll 1
    for (int l = 0; l < 5; ++l) {
        phase_body<0>(gmat, st, wrp, wip, sb, af, swcb, swba, f4l, lane, w, tid, l, 4, true, outp);
        phase_body<1>(gmat, st, wrp, wip, sb, af, swcb, swba, f4l, lane, w, tid, l, 8, true, outp);
        phase_body<2>(gmat, st, wrp, wip, sb, af, swcb, swba, f4l, lane, w, tid, l + 1, 0, true, outp);
    }
    phase_body<0>(gmat, st, wrp, wip, sb, af, swcb, swba, f4l, lane, w, tid, 5, 4, true, outp);
    phase_body<1>(gmat, st, wrp, wip, sb, af, swcb, swba, f4l, lane, w, tid, 5, 8, true, outp);
    phase_body<3>(gmat, st, wrp, wip, sb, af, swcb, swba, f4l, lane, w, tid, 0, 0, false, outp);
}

extern "C" void kernel_launch(void* const* d_in, const int* in_sizes, int n_in,
                              void* d_out, int out_size, void* d_ws, size_t ws_size,
                              hipStream_t stream) {
    const float* x = (const float*)d_in[0];      // [1024, 4096] f32
    const float* wgt = (const float*)d_in[1];    // [216] f32
    float* out = (float*)d_out;                  // [1024, 4096] f32
    qsim_kernel<<<dim3(1024), dim3(TPB), 0, stream>>>(x, wgt, out);
}

// Round 9
// 34.767 us; speedup vs baseline: 2.2072x; 1.4835x over previous
//
#include <hip/hip_runtime.h>
#include <math.h>

#define NQ 12
#define NLAYERS 5
#define TPB 256

typedef float v4f __attribute__((ext_vector_type(4)));
typedef short v8s __attribute__((ext_vector_type(8)));

#define MFMA(A, B, C) __builtin_amdgcn_mfma_f32_16x16x32_bf16((A), (B), (C), 0, 0, 0)

// ---- complex helpers (gate/W build) ----
__device__ __forceinline__ float2 cmulf(float2 a, float2 b) {
    return make_float2(a.x * b.x - a.y * b.y, a.x * b.y + a.y * b.x);
}
__device__ __forceinline__ float2 caddf(float2 a, float2 b) {
    return make_float2(a.x + b.x, a.y + b.y);
}
__device__ __forceinline__ void mat2mul(const float2 A[4], const float2 B[4], float2 C[4]) {
    C[0] = caddf(cmulf(A[0], B[0]), cmulf(A[1], B[2]));
    C[1] = caddf(cmulf(A[0], B[1]), cmulf(A[1], B[3]));
    C[2] = caddf(cmulf(A[2], B[0]), cmulf(A[3], B[2]));
    C[3] = caddf(cmulf(A[2], B[1]), cmulf(A[3], B[3]));
}

__device__ __forceinline__ v8s pk4(unsigned a, unsigned b, unsigned c, unsigned d) {
    union { unsigned u[4]; v8s s; } x;
    x.u[0] = a; x.u[1] = b; x.u[2] = c; x.u[3] = d;
    return x.s;
}
__device__ __forceinline__ unsigned cvt2(float a, float b) {   // {bf16(a) lo16, bf16(b) hi16}
    unsigned d;
    asm("v_cvt_pk_bf16_f32 %0, %1, %2" : "=v"(d) : "v"(a), "v"(b));
    return d;
}
// f32 -> {bf16rne(f) lo16, bf16(f - hi) hi16}  (split-W: hi+lo ~ 18-bit exact)
__device__ __forceinline__ unsigned packhl_rne(float f) {
    unsigned h = cvt2(f, 0.0f);
    float lo = f - __uint_as_float(h << 16);
    unsigned l = cvt2(lo, 0.0f);
    return h | (l << 16);
}

// ---- ring-of-CNOT permutation p = y^{-1} (HW-verified in R8) ----
__device__ __forceinline__ int sx4(int x) { x ^= x >> 1; x ^= x >> 2; return x & 15; }
__device__ __forceinline__ int permR(int row) {
    int s = sx4(row), par = s & 1;
    return ((s ^ (par << 3)) << 8) | (par ? 0xFF : 0);
}
__device__ __forceinline__ int permT(int t) {
    int s = sx4(t), par = s & 1;
    return (par << 11) | (s << 4) | (par ? 0xF : 0);
}
__device__ __forceinline__ int permL(int lo) {
    int s = sx4(lo), par = s & 1;
    return s | (par << 11);
}

// ---- GF(2)-linear slot keying: kappa = v<<4 | m (m = group to contract) ----
// slot = vk(v)<<4 | ((m[3:2]^v[1:0])<<2) | m[1:0];  vk = v ^ ((v3^v7)&1)
// -> b128 state reads & quad initial writes contiguous; all patterns <=2-way banks
__device__ __forceinline__ int slotOf(int k) {
    int v = k >> 4, m = k & 15;
    int vk = v ^ (((v >> 3) ^ (v >> 7)) & 1);
    return (vk << 4) | ((((m >> 2) ^ v) & 3) << 2) | (m & 3);
}

// W = Kron of 4 gates (qubits 11-beta-0..3); thread -> entry (r=tid>>4, c=tid&15)
__device__ __forceinline__ void buildW(const float2* gm, int layer, int beta, int tid,
                                       unsigned& wrd, unsigned& wid) {
    const int r = tid >> 4, c = tid & 15;
    float2 u = make_float2(1.f, 0.f);
    #pragma unroll
    for (int bb = 0; bb < 4; ++bb) {
        const float2 e = gm[(layer * 12 + 11 - beta - bb) * 4 + ((r >> bb) & 1) * 2 + ((c >> bb) & 1)];
        u = cmulf(u, e);
    }
    wrd = packhl_rne(u.x);
    wid = packhl_rne(u.y);
}

// One phase. WM: 0 = normal rotate-write, 1 = rotate+CNOT-perm write, 2 = final global.
template<int WM, bool DOB>
__device__ __forceinline__ void phase_run(
    unsigned* __restrict__ st, unsigned* __restrict__ wrp, unsigned* __restrict__ wip,
    const float2* __restrict__ gm, float* __restrict__ outp,
    int rbase, int af, const int (&bw)[4], const int (&pg)[4], const int (&pt)[4],
    int obase, int tid, int bl, int bb)
{
    // A fragments: combine {Wr,-Wi} (for Cr) and {Wi,Wr} (for Ci), h and l parts.
    const uint4 wr4 = *reinterpret_cast<const uint4*>(wrp + af);
    const uint4 wi4 = *reinterpret_cast<const uint4*>(wip + af);

    // state reads: 4x b128, dword d = amp (4hl+d) = {Sr lo16, Si hi16}
    uint4 s0 = *reinterpret_cast<const uint4*>(st + rbase);
    uint4 s1 = *reinterpret_cast<const uint4*>(st + rbase + 256);
    uint4 s2 = *reinterpret_cast<const uint4*>(st + rbase + 512);
    uint4 s3 = *reinterpret_cast<const uint4*>(st + rbase + 768);

    const unsigned NX = 0x80008000u;
    const unsigned SLO = 0x05040100u, SHI = 0x07060302u;
    unsigned n0 = wi4.x ^ NX, n1 = wi4.y ^ NX, n2 = wi4.z ^ NX, n3 = wi4.w ^ NX;
    const v8s a_crh = pk4(__builtin_amdgcn_perm(n0, wr4.x, SLO), __builtin_amdgcn_perm(n1, wr4.y, SLO),
                          __builtin_amdgcn_perm(n2, wr4.z, SLO), __builtin_amdgcn_perm(n3, wr4.w, SLO));
    const v8s a_crl = pk4(__builtin_amdgcn_perm(n0, wr4.x, SHI), __builtin_amdgcn_perm(n1, wr4.y, SHI),
                          __builtin_amdgcn_perm(n2, wr4.z, SHI), __builtin_amdgcn_perm(n3, wr4.w, SHI));
    const v8s a_cih = pk4(__builtin_amdgcn_perm(wr4.x, wi4.x, SLO), __builtin_amdgcn_perm(wr4.y, wi4.y, SLO),
                          __builtin_amdgcn_perm(wr4.z, wi4.z, SLO), __builtin_amdgcn_perm(wr4.w, wi4.w, SLO));
    const v8s a_cil = pk4(__builtin_amdgcn_perm(wr4.x, wi4.x, SHI), __builtin_amdgcn_perm(wr4.y, wi4.y, SHI),
                          __builtin_amdgcn_perm(wr4.z, wi4.z, SHI), __builtin_amdgcn_perm(wr4.w, wi4.w, SHI));

    const v4f z = {0.f, 0.f, 0.f, 0.f};
    unsigned ent[4][4];
    #pragma unroll
    for (int ti = 0; ti < 4; ++ti) {
        const uint4 sv = (ti == 0) ? s0 : (ti == 1) ? s1 : (ti == 2) ? s2 : s3;
        const v8s bsv = pk4(sv.x, sv.y, sv.z, sv.w);
        v4f cr = MFMA(a_crl, bsv, z);
        cr = MFMA(a_crh, bsv, cr);
        if (WM == 2) {
            #pragma unroll
            for (int g = 0; g < 4; ++g)
                outp[obase + (g << 8) + (ti << 4)] = cr[g];
        } else {
            v4f ci = MFMA(a_cil, bsv, z);
            ci = MFMA(a_cih, bsv, ci);
            #pragma unroll
            for (int g = 0; g < 4; ++g)
                ent[ti][g] = cvt2(cr[g], ci[g]);
        }
    }
    if (WM == 2) return;   // final: no LDS writes, kernel ends

    unsigned wrd = 0, wid = 0;
    if (DOB) buildW(gm, bl, bb, tid, wrd, wid);

    __syncthreads();   // all reads of st/W done -> safe to overwrite

    if (DOB) { wrp[tid] = wrd; wip[tid] = wid; }
    #pragma unroll
    for (int ti = 0; ti < 4; ++ti) {
        #pragma unroll
        for (int g = 0; g < 4; ++g) {
            if (WM == 0) st[bw[ti] + (g << 8)] = ent[ti][g];
            else         st[pg[g] ^ pt[ti]]    = ent[ti][g];
        }
    }
    __syncthreads();
}

__global__ __launch_bounds__(TPB) void qsim_kernel(const float* __restrict__ x,
                                                   const float* __restrict__ wgt,
                                                   float* __restrict__ out) {
    __shared__ __align__(16) unsigned st[4096];    // 16 KB: {bf16 re, bf16 im} per amp
    __shared__ __align__(16) unsigned wrp[256];    // 1 KB: W real {hi,lo}
    __shared__ __align__(16) unsigned wip[256];    // 1 KB: W imag {hi,lo}
    __shared__ __align__(16) float2 gmat[288];     // fused 2x2 gates (f32, exact)
    __shared__ float red[4];

    const int tid = threadIdx.x;
    const int lane = tid & 63;
    const int w = tid >> 6;
    const int hl = lane >> 4;
    const int l15 = lane & 15;
    const int b = blockIdx.x;

    // ---- fused per-qubit gate matrices (threads 0..71) ----
    if (tid < 72) {
        const int l = tid / NQ;
        const int q = tid % NQ;
        const float* pp = wgt + (l < NLAYERS ? l * (3 * NQ) : NLAYERS * (3 * NQ)) + q * 3;
        float s0, c0, s1, c1, s2, c2;
        sincosf(0.5f * pp[0], &s0, &c0);
        sincosf(0.5f * pp[1], &s1, &c1);
        sincosf(0.5f * pp[2], &s2, &c2);
        float2 U[4], M[4];
        if (l < NLAYERS) {
            float2 RX[4] = { {c0, 0.f}, {0.f, -s0}, {0.f, -s0}, {c0, 0.f} };
            float2 RY[4] = { {c1, 0.f}, {-s1, 0.f}, {s1, 0.f}, {c1, 0.f} };
            float2 RZ[4] = { {c2, -s2}, {0.f, 0.f}, {0.f, 0.f}, {c2, s2} };
            mat2mul(RY, RX, M);
            mat2mul(RZ, M, U);
        } else {
            float2 RY0[4] = { {c0, 0.f}, {-s0, 0.f}, {s0, 0.f}, {c0, 0.f} };
            float2 RZ1[4] = { {c1, -s1}, {0.f, 0.f}, {0.f, 0.f}, {c1, s1} };
            float2 RY2[4] = { {c2, 0.f}, {-s2, 0.f}, {s2, 0.f}, {c2, 0.f} };
            mat2mul(RZ1, RY0, M);
            mat2mul(RY2, M, U);
        }
        gmat[tid * 4 + 0] = U[0];
        gmat[tid * 4 + 1] = U[1];
        gmat[tid * 4 + 2] = U[2];
        gmat[tid * 4 + 3] = U[3];
    }

    // ---- load x (i = 16*tid + j), sum of squares ----
    const float* xb = x + (size_t)b * 4096;
    float vals[16];
    float ss = 0.f;
    {
        const float4* xv = reinterpret_cast<const float4*>(xb + 16 * tid);
        #pragma unroll
        for (int k = 0; k < 4; ++k) {
            float4 v = xv[k];
            vals[k * 4 + 0] = v.x; vals[k * 4 + 1] = v.y;
            vals[k * 4 + 2] = v.z; vals[k * 4 + 3] = v.w;
            ss += v.x * v.x + v.y * v.y + v.z * v.z + v.w * v.w;
        }
    }
    #pragma unroll
    for (int off = 32; off > 0; off >>= 1) ss += __shfl_down(ss, off, 64);
    if (lane == 0) red[w] = ss;
    __syncthreads();   // gmat + red visible

    const float total = red[0] + red[1] + red[2] + red[3];
    const float inv = 1.0f / sqrtf(sqrtf(total) + 1e-12f);

    // ---- initial state (true-id keyed: kappa = i, v = tid, m = j): 4x b128 ----
    const int vkT = tid ^ (((tid >> 3) ^ (tid >> 7)) & 1);
    #pragma unroll
    for (int jq = 0; jq < 4; ++jq) {
        const int base = (vkT << 4) | (((jq ^ tid) & 3) << 2);
        uint4 eq;
        eq.x = cvt2(vals[jq * 4 + 0] * inv, 0.f);
        eq.y = cvt2(vals[jq * 4 + 1] * inv, 0.f);
        eq.z = cvt2(vals[jq * 4 + 2] * inv, 0.f);
        eq.w = cvt2(vals[jq * 4 + 3] * inv, 0.f);
        *reinterpret_cast<uint4*>(st + base) = eq;
    }

    // ---- W for phase 1 (layer 0, beta 0) ----
    {
        unsigned wrd, wid;
        buildW(gmat, 0, 0, tid, wrd, wid);
        wrp[tid] = wrd; wip[tid] = wid;
    }
    __syncthreads();

    // ---- per-thread address constants ----
    // read: kappa = ((4w+ti)<<4 | l15)<<4 | (4hl+d): base for ti=0, +256/ti
    const int v0 = (w << 6) | l15;
    const int vk0 = v0 ^ ((((v0 >> 3) ^ (v0 >> 7)) & 1));
    const int rbase = (vk0 << 4) | ((hl ^ (l15 & 3)) << 2);
    const int af = l15 * 16 + 4 * hl;
    int bw[4], pg[4], pt[4];
    const int sgb = slotOf((4 * hl) << 8);
    const int plc = slotOf(permL(l15));
    #pragma unroll
    for (int ti = 0; ti < 4; ++ti) {
        bw[ti] = sgb ^ slotOf((((4 * w + ti) << 4) | l15));
        pt[ti] = plc ^ slotOf(permT(4 * w + ti));
    }
    #pragma unroll
    for (int g = 0; g < 4; ++g) pg[g] = slotOf(permR(4 * hl + g));
    const int obase = ((4 * hl) << 8) | ((4 * w) << 4) | l15;
    float* outp = out + (size_t)b * 4096;

    // ---- 18 phases: 6 layers x {beta 0, 4, 8}; perm fused into layer-end write ----
    #pragma unroll 1
    for (int l = 0; l < 5; ++l) {
        phase_run<0, true>(st, wrp, wip, gmat, outp, rbase, af, bw, pg, pt, obase, tid, l, 4);
        phase_run<0, true>(st, wrp, wip, gmat, outp, rbase, af, bw, pg, pt, obase, tid, l, 8);
        phase_run<1, true>(st, wrp, wip, gmat, outp, rbase, af, bw, pg, pt, obase, tid, l + 1, 0);
    }
    phase_run<0, true>(st, wrp, wip, gmat, outp, rbase, af, bw, pg, pt, obase, tid, 5, 4);
    phase_run<0, true>(st, wrp, wip, gmat, outp, rbase, af, bw, pg, pt, obase, tid, 5, 8);
    phase_run<2, false>(st, wrp, wip, gmat, outp, rbase, af, bw, pg, pt, obase, tid, 0, 0);
}

extern "C" void kernel_launch(void* const* d_in, const int* in_sizes, int n_in,
                              void* d_out, int out_size, void* d_ws, size_t ws_size,
                              hipStream_t stream) {
    const float* x = (const float*)d_in[0];      // [1024, 4096] f32
    const float* wgt = (const float*)d_in[1];    // [216] f32
    float* out = (float*)d_out;                  // [1024, 4096] f32
    qsim_kernel<<<dim3(1024), dim3(TPB), 0, stream>>>(x, wgt, out);
}